// Round 10
// baseline (1022.814 us; speedup 1.0000x reference)
//
#include <hip/hip_runtime.h>
#include <hip/hip_bf16.h>

typedef __bf16 v8bf  __attribute__((ext_vector_type(8)));
typedef __bf16 v4bf  __attribute__((ext_vector_type(4)));
typedef float  f32x4 __attribute__((ext_vector_type(4)));
typedef float  f32x8 __attribute__((ext_vector_type(8)));
typedef float  f32x16 __attribute__((ext_vector_type(16)));

#define TOKENS 50176
#define CDIM   576
#define NHEAD  18
#define QKVD   1728

// async global->LDS, 16B per lane; LDS dest = wave-uniform base + lane*16
__device__ __forceinline__ void gld16(const __bf16* g, __bf16* l)
{
    __builtin_amdgcn_global_load_lds(
        (const __attribute__((address_space(1))) void*)g,
        (__attribute__((address_space(3))) void*)l,
        16, 0, 0);
}

// exact-GELU via Abramowitz-Stegun 7.1.26 erf (|err| <= 1.5e-7, below bf16 eps)
__device__ __forceinline__ float fast_gelu(float x)
{
    const float z  = x * 0.70710678118654752f;
    const float az = fabsf(z);
    const float t  = __frcp_rn(1.0f + 0.3275911f * az);
    float p = 1.061405429f;
    p = p * t - 1.453152027f;
    p = p * t + 1.421413741f;
    p = p * t - 0.284496736f;
    p = p * t + 0.254829592f;
    const float e   = __expf(-z * z);
    float erfv = 1.0f - p * t * e;
    erfv = copysignf(erfv, z);
    return 0.5f * x * (1.0f + erfv);
}

// ---------------- f32 -> bf16 cast (weights), 4 elems/thread ----------------
__global__ __launch_bounds__(256)
void cast_kernel(const float* __restrict__ in, __bf16* __restrict__ out)
{
    const size_t i = ((size_t)blockIdx.x * 256 + threadIdx.x) * 4;
    f32x4 v = *(const f32x4*)&in[i];
    v4bf o;
#pragma unroll
    for (int j = 0; j < 4; ++j) o[j] = (__bf16)v[j];
    *(v4bf*)&out[i] = o;
}

// ------- conv weight prep: fold BN scale into weights, make [9][576] bf16 -------
__global__ __launch_bounds__(64)
void conv_prep(const float* __restrict__ w, const float* __restrict__ bg,
               const float* __restrict__ bb, const float* __restrict__ bm,
               const float* __restrict__ bv, __bf16* __restrict__ wt,
               float* __restrict__ bias2)
{
    const int c = blockIdx.x * 64 + threadIdx.x;   // 576
    const float inv = rsqrtf(bv[c] + 1e-5f) * bg[c];
#pragma unroll
    for (int t = 0; t < 9; ++t) wt[t * CDIM + c] = (__bf16)(w[c * 9 + t] * inv);
    bias2[c] = bb[c] - bm[c] * inv;
}

// ---------------- LayerNorm: one wave per token, C=576; InT in, bf16 out ----
template<typename InT>
__global__ __launch_bounds__(256)
void ln_kernel(const InT* __restrict__ x, const float* __restrict__ g,
               const float* __restrict__ b, __bf16* __restrict__ out)
{
    const int lane = threadIdx.x & 63;
    const int wid  = threadIdx.x >> 6;
    const size_t t = (size_t)blockIdx.x * 4 + wid;
    const InT* row = x + t * CDIM;

    float v[16];
    float sum = 0.f, sq = 0.f;
    if constexpr (sizeof(InT) == 2) {
        v8bf d0 = *(const v8bf*)&row[(size_t)lane * 8];
#pragma unroll
        for (int j = 0; j < 8; ++j) { float f = (float)d0[j]; v[j] = f; sum += f; sq += f * f; }
    } else {
        f32x8 d0 = *(const f32x8*)&row[(size_t)lane * 8];
#pragma unroll
        for (int j = 0; j < 8; ++j) { float f = d0[j]; v[j] = f; sum += f; sq += f * f; }
    }
    if (lane < 8) {
        if constexpr (sizeof(InT) == 2) {
            v8bf d1 = *(const v8bf*)&row[(size_t)(lane + 64) * 8];
#pragma unroll
            for (int j = 0; j < 8; ++j) { float f = (float)d1[j]; v[8 + j] = f; sum += f; sq += f * f; }
        } else {
            f32x8 d1 = *(const f32x8*)&row[(size_t)(lane + 64) * 8];
#pragma unroll
            for (int j = 0; j < 8; ++j) { float f = d1[j]; v[8 + j] = f; sum += f; sq += f * f; }
        }
    }
#pragma unroll
    for (int o = 32; o >= 1; o >>= 1) {
        sum += __shfl_xor(sum, o, 64);
        sq  += __shfl_xor(sq,  o, 64);
    }
    const float mean = sum * (1.0f / CDIM);
    const float rstd = rsqrtf(sq * (1.0f / CDIM) - mean * mean + 1e-5f);

    {
        int c0 = lane * 8;
        v8bf o0;
#pragma unroll
        for (int j = 0; j < 8; ++j)
            o0[j] = (__bf16)((v[j] - mean) * rstd * g[c0 + j] + b[c0 + j]);
        *(v8bf*)&out[t * CDIM + c0] = o0;
    }
    if (lane < 8) {
        int c0 = (lane + 64) * 8;
        v8bf o1;
#pragma unroll
        for (int j = 0; j < 8; ++j)
            o1[j] = (__bf16)((v[8 + j] - mean) * rstd * g[c0 + j] + b[c0 + j]);
        *(v8bf*)&out[t * CDIM + c0] = o1;
    }
}

// ------- GEMM: C[M][N] = A[M][K] @ W[N][K]^T + bias, optional epilogue -------
// mfma_f32_32x32x16_bf16 (halves LDS fragment bytes per FLOP vs 16x16x32).
// Block 256x192, 4 waves (2Mx2N), wave tile 128x96 = 4x3 frags of 32x32
// (acc 192 VGPR). Ring-2 LDS (56KB) -> 2 blocks/CU at <=256 VGPR: cross-block
// TLP covers the per-tile vmcnt(0) drain. Per tile: s0 ds_reads -> stage(t+1)
// -> s0 MFMA -> s1 ds_reads -> s1 MFMA -> vmcnt(0) -> barrier (4-wave barrier).
// LDS cells: 1KB = 32 rows x 16 k, lane-linear (row=lane&31, k=(lane>>5)*8):
// matches the 32x32x16 A/B fragment layout exactly -> conflict-free b128 reads
// and linear global_load_lds dests. 192 divides N in {576,1728,2304}.
// EPI: 0 = none, 1 = += add[M][N], 2 = exact GELU
template<int EPI, typename OutT, typename AddT>
__global__ __launch_bounds__(256, 2)
void gemm_bt(const __bf16* __restrict__ A, const __bf16* __restrict__ W,
             const float* __restrict__ bias, const AddT* __restrict__ add,
             OutT* __restrict__ C, int N, int K, int nN)
{
    constexpr int BK = 32;
    constexpr int ASZ = 256 * BK;         // 8192 elems (16 cells)
    constexpr int BSZ = 192 * BK;         // 6144 elems (12 cells)
    __shared__ __bf16 L[2][ASZ + BSZ];    // 2 x 28 KB = 56 KB
    const int tid = threadIdx.x, lane = tid & 63, wid = tid >> 6;
    const int l31 = lane & 31, kg = lane >> 5;   // frag row/col & k-group
    const int wm = wid >> 1, wn = wid & 1;       // wave grid 2(M) x 2(N)

    // XCD-chunked bijective swizzle (m204), N-fastest decode
    const int nwg = gridDim.x, bid = blockIdx.x;
    const int q = nwg >> 3, r = nwg & 7;
    const int xcd = bid & 7, jc = bid >> 3;
    const int wgid = (xcd < r ? xcd * (q + 1) : r * (q + 1) + (xcd - r) * q) + jc;
    const int mblk = wgid / nN, nblk = wgid - mblk * nN;
    const int m0 = mblk * 256, n0 = nblk * 192;

    // per-lane staging bases (row = l31, k-group = kg)
    const __bf16* pAl = A + (size_t)(m0 + l31) * K + kg * 8;
    const __bf16* pWl = W + (size_t)(n0 + l31) * K + kg * 8;

    // 28 gld16 per tile (A:16 cells, B:12), 7 per wave
    auto stage = [&](int s, int kt) {
        const int kk = kt * BK;
#pragma unroll
        for (int i = 0; i < 7; ++i) {
            const int e = wid + 4 * i;          // 0..27, unique per (wid,i)
            if (e < 16) {                        // A cell: g=e>>1 rows, h=e&1 k-half
                gld16(pAl + (size_t)((e >> 1) * 32) * K + kk + (e & 1) * 16,
                      &L[s][e * 512]);
            } else {
                const int e2 = e - 16;
                gld16(pWl + (size_t)((e2 >> 1) * 32) * K + kk + (e2 & 1) * 16,
                      &L[s][ASZ + e2 * 512]);
            }
        }
    };

    const int lo = lane * 8;   // lane offset within cell (elems)

    f32x16 acc[4][3] = {};
    const int NT = K / BK;

    stage(0, 0);
    asm volatile("s_waitcnt vmcnt(0)" ::: "memory");
    __builtin_amdgcn_s_barrier();

    int cur = 0;
    for (int t = 0; t < NT; ++t) {
        const __bf16* Ls = L[cur];
        v8bf a0[4], b0[3];
        // ---- k-sub 0 reads ----
#pragma unroll
        for (int mf = 0; mf < 4; ++mf)
            a0[mf] = *(const v8bf*)&Ls[((wm * 4 + mf) * 2 + 0) * 512 + lo];
#pragma unroll
        for (int nf = 0; nf < 3; ++nf)
            b0[nf] = *(const v8bf*)&Ls[ASZ + ((wn * 3 + nf) * 2 + 0) * 512 + lo];

        if (t + 1 < NT) stage(cur ^ 1, t + 1);   // in flight across MFMA phases

        __builtin_amdgcn_s_setprio(1);
#pragma unroll
        for (int mf = 0; mf < 4; ++mf)
#pragma unroll
            for (int nf = 0; nf < 3; ++nf)
                acc[mf][nf] = __builtin_amdgcn_mfma_f32_32x32x16_bf16(
                    a0[mf], b0[nf], acc[mf][nf], 0, 0, 0);
        __builtin_amdgcn_s_setprio(0);

        // ---- k-sub 1 reads + MFMA ----
        v8bf a1[4], b1[3];
#pragma unroll
        for (int mf = 0; mf < 4; ++mf)
            a1[mf] = *(const v8bf*)&Ls[((wm * 4 + mf) * 2 + 1) * 512 + lo];
#pragma unroll
        for (int nf = 0; nf < 3; ++nf)
            b1[nf] = *(const v8bf*)&Ls[ASZ + ((wn * 3 + nf) * 2 + 1) * 512 + lo];

        __builtin_amdgcn_s_setprio(1);
#pragma unroll
        for (int mf = 0; mf < 4; ++mf)
#pragma unroll
            for (int nf = 0; nf < 3; ++nf)
                acc[mf][nf] = __builtin_amdgcn_mfma_f32_32x32x16_bf16(
                    a1[mf], b1[nf], acc[mf][nf], 0, 0, 0);
        __builtin_amdgcn_s_setprio(0);

        if (t + 1 < NT) {
            asm volatile("s_waitcnt vmcnt(0)" ::: "memory");  // stage(t+1) landed
            __builtin_amdgcn_s_barrier();                     // all done reading cur
            cur ^= 1;
        }
    }

    // ---- epilogue: C/D layout col=lane&31, row=(r&3)+8*(r>>2)+4*kg ----
    float bc[3];
#pragma unroll
    for (int nf = 0; nf < 3; ++nf) bc[nf] = bias[n0 + wn * 96 + nf * 32 + l31];

#pragma unroll
    for (int mf = 0; mf < 4; ++mf)
#pragma unroll
        for (int nf = 0; nf < 3; ++nf) {
            const int col = n0 + wn * 96 + nf * 32 + l31;
#pragma unroll
            for (int rr = 0; rr < 16; ++rr) {
                const int row = m0 + wm * 128 + mf * 32 + (rr & 3) + 8 * (rr >> 2) + 4 * kg;
                float vv = acc[mf][nf][rr] + bc[nf];
                if (EPI == 1) vv += (float)add[(size_t)row * N + col];
                if (EPI == 2) vv = fast_gelu(vv);
                C[(size_t)row * N + col] = (OutT)vv;
            }
        }
}

// ---------------- Windowed attention: one wave per (head, window) ----------------
__global__ __launch_bounds__(64)
void attn_kernel(const __bf16* __restrict__ qkv, const float* __restrict__ biases,
                 const int* __restrict__ bidx, __bf16* __restrict__ out)
{
    const int head = blockIdx.x;
    const int win  = blockIdx.y;
    const int tid  = threadIdx.x;
    const int b  = win >> 4;
    const int wy = (win >> 2) & 3;
    const int wx = win & 3;
    __shared__ float kk[49][32];
    __shared__ float vv[49][32];
    const size_t hb = (size_t)head * 96;

    for (int e = tid; e < 49 * 32; e += 64) {
        int n = e >> 5, d = e & 31;
        int iy = n / 7, ix = n - iy * 7;
        size_t t = (size_t)b * 784 + (size_t)(wy * 7 + iy) * 28 + wx * 7 + ix;
        const __bf16* p = qkv + t * QKVD + hb;
        kk[n][d] = (float)p[32 + d];
        vv[n][d] = (float)p[64 + d];
    }
    float q[32];
    size_t tmine = 0;
    if (tid < 49) {
        int iy = tid / 7, ix = tid - iy * 7;
        tmine = (size_t)b * 784 + (size_t)(wy * 7 + iy) * 28 + wx * 7 + ix;
        const __bf16* p = qkv + tmine * QKVD + hb;
#pragma unroll
        for (int d = 0; d < 32; ++d) q[d] = (float)p[d];
    }
    __syncthreads();
    if (tid >= 49) return;

    const float scale = 0.17677669529663687f;
    float s[49];
    float mx = -1e30f;
    const int*   brow = bidx + tid * 49;
    const float* bh   = biases + head * 49;
#pragma unroll
    for (int m = 0; m < 49; ++m) {
        float dot = 0.f;
#pragma unroll
        for (int d = 0; d < 32; ++d) dot += q[d] * kk[m][d];
        float val = dot * scale + bh[brow[m]];
        s[m] = val;
        mx = fmaxf(mx, val);
    }
    float sum = 0.f;
#pragma unroll
    for (int m = 0; m < 49; ++m) { float e = __expf(s[m] - mx); s[m] = e; sum += e; }
    const float rs = 1.0f / sum;

    __bf16* op = out + tmine * CDIM + (size_t)head * 32;
#pragma unroll
    for (int d = 0; d < 32; ++d) {
        float a = 0.f;
#pragma unroll
        for (int m = 0; m < 49; ++m) a += s[m] * vv[m][d];
        op[d] = (__bf16)(a * rs);
    }
}

// ------- Depthwise 3x3 conv + folded BN, vectorized: 8 channels/thread -------
__global__ __launch_bounds__(256)
void conv_bn_v(const __bf16* __restrict__ xin, const __bf16* __restrict__ wt,
               const float* __restrict__ bias2, __bf16* __restrict__ xout)
{
    const size_t gt = (size_t)blockIdx.x * 256 + threadIdx.x;
    const int g = (int)(gt % 72);
    const size_t p = gt / 72;
    const int bimg = (int)(p / 784);
    const int pix  = (int)(p - (size_t)bimg * 784);
    const int y = pix / 28, xx = pix - y * 28;
    const int c0 = g * 8;

    float acc[8];
    {
        f32x4 b0 = *(const f32x4*)&bias2[c0];
        f32x4 b1 = *(const f32x4*)&bias2[c0 + 4];
#pragma unroll
        for (int jj = 0; jj < 4; ++jj) { acc[jj] = b0[jj]; acc[4 + jj] = b1[jj]; }
    }
#pragma unroll
    for (int dy = 0; dy < 3; ++dy) {
        int ny = y + dy - 1;
        if (ny < 0 || ny >= 28) continue;
#pragma unroll
        for (int dx = 0; dx < 3; ++dx) {
            int nx = xx + dx - 1;
            if (nx < 0 || nx >= 28) continue;
            v8bf xv = *(const v8bf*)&xin[((size_t)bimg * 784 + ny * 28 + nx) * CDIM + c0];
            v8bf wv = *(const v8bf*)&wt[(dy * 3 + dx) * CDIM + c0];
#pragma unroll
            for (int jj = 0; jj < 8; ++jj) acc[jj] += (float)xv[jj] * (float)wv[jj];
        }
    }
    v8bf o;
#pragma unroll
    for (int jj = 0; jj < 8; ++jj) o[jj] = (__bf16)acc[jj];
    *(v8bf*)&xout[p * CDIM + c0] = o;
}

extern "C" void kernel_launch(void* const* d_in, const int* in_sizes, int n_in,
                              void* d_out, int out_size, void* d_ws, size_t ws_size,
                              hipStream_t stream)
{
    (void)in_sizes; (void)n_in; (void)out_size; (void)ws_size;
    const float* x          = (const float*)d_in[0];
    const float* gamma_a    = (const float*)d_in[1];
    const float* beta_a     = (const float*)d_in[2];
    const float* qkv_w      = (const float*)d_in[3];
    const float* qkv_b      = (const float*)d_in[4];
    const float* proj_w     = (const float*)d_in[5];
    const float* proj_b     = (const float*)d_in[6];
    const float* attn_bias  = (const float*)d_in[7];
    const float* conv_w     = (const float*)d_in[8];
    const float* bn_g       = (const float*)d_in[9];
    const float* bn_b       = (const float*)d_in[10];
    const float* bn_m       = (const float*)d_in[11];
    const float* bn_v       = (const float*)d_in[12];
    const float* gamma_m    = (const float*)d_in[13];
    const float* beta_m     = (const float*)d_in[14];
    const float* fc1_w      = (const float*)d_in[15];
    const float* fc1_b      = (const float*)d_in[16];
    const float* fc2_w      = (const float*)d_in[17];
    const float* fc2_b      = (const float*)d_in[18];
    const int*   bidx       = (const int*)d_in[19];

    const size_t T = TOKENS;
    __bf16* ws     = (__bf16*)d_ws;
    __bf16* hbuf   = ws;
    __bf16* qkvbuf = ws + T * 576;
    __bf16* aout   = ws;                 // reuse hbuf
    __bf16* x2     = ws + T * 2304;
    __bf16* x3     = x2 + T * 576;
    __bf16* lnm    = x2;                 // reuse (x2 dead after conv_bn)
    __bf16* f1     = ws;                 // reuse R0
    __bf16* wq     = x3 + T * 576;                   // qkv_w bf16  [1728*576]
    __bf16* wp     = wq + (size_t)QKVD * CDIM;       // proj_w bf16 [576*576]
    __bf16* w1     = wp + (size_t)CDIM * CDIM;       // fc1_w bf16  [2304*576]
    __bf16* w2     = w1 + (size_t)2304 * CDIM;       // fc2_w bf16  [576*2304]
    __bf16* wt     = w2 + (size_t)CDIM * 2304;       // conv wt [9][576]
    float*  bias2  = (float*)(wt + 9 * CDIM);        // conv bias [576]
    float*  outp   = (float*)d_out;

    cast_kernel<<<dim3((QKVD * CDIM) / 1024), 256, 0, stream>>>(qkv_w, wq);
    cast_kernel<<<dim3((CDIM * CDIM) / 1024), 256, 0, stream>>>(proj_w, wp);
    cast_kernel<<<dim3((2304 * CDIM) / 1024), 256, 0, stream>>>(fc1_w, w1);
    cast_kernel<<<dim3((CDIM * 2304) / 1024), 256, 0, stream>>>(fc2_w, w2);
    conv_prep<<<dim3(9), 64, 0, stream>>>(conv_w, bn_g, bn_b, bn_m, bn_v, wt, bias2);

    ln_kernel<float><<<dim3(T / 4), 256, 0, stream>>>(x, gamma_a, beta_a, hbuf);
    gemm_bt<0, __bf16, float><<<dim3(196 * 9), 256, 0, stream>>>(
        hbuf, wq, qkv_b, nullptr, qkvbuf, QKVD, CDIM, 9);
    attn_kernel<<<dim3(NHEAD, 1024), 64, 0, stream>>>(qkvbuf, attn_bias, bidx, aout);
    gemm_bt<1, __bf16, float><<<dim3(196 * 3), 256, 0, stream>>>(
        aout, wp, proj_b, x, x2, CDIM, CDIM, 3);
    conv_bn_v<<<dim3(14112), 256, 0, stream>>>(x2, wt, bias2, x3);
    ln_kernel<__bf16><<<dim3(T / 4), 256, 0, stream>>>(x3, gamma_m, beta_m, lnm);
    gemm_bt<2, __bf16, float><<<dim3(196 * 12), 256, 0, stream>>>(
        lnm, w1, fc1_b, nullptr, f1, 2304, CDIM, 12);
    gemm_bt<1, float, __bf16><<<dim3(196 * 3), 256, 0, stream>>>(
        f1, w2, fc2_b, x3, outp, CDIM, 2304, 3);
}